// Round 7
// baseline (295.595 us; speedup 1.0000x reference)
//
#include <hip/hip_runtime.h>
#include <hip/hip_bf16.h>

#define CIN 1024
#define HW2 9216
#define COUT 256
#define NSH 4
#define RHID 64
#define CPG 8
#define EPSV 1e-5f
#define GRPSZ (CPG * HW2)

typedef __attribute__((ext_vector_type(8))) short bf16x8;
typedef __attribute__((ext_vector_type(4))) float f32x4;

__device__ __forceinline__ unsigned short f2bf(float f) {
  unsigned u = __builtin_bit_cast(unsigned, f);
  u = (u + 0x7fffu + ((u >> 16) & 1u)) >> 16;
  return (unsigned short)u;
}
__device__ __forceinline__ float bf2f(unsigned short h) {
  unsigned u = (unsigned)h << 16;
  return __builtin_bit_cast(float, u);
}

// ---- kernel 1: GAP row sums (writes pooled directly; zeroes stpart) --------
__global__ __launch_bounds__(256) void k_pool(
    const float* __restrict__ feat, float* __restrict__ pooled,
    float* __restrict__ stpart) {
  int row = blockIdx.x;            // 8192 = b*CIN + c
  if (row == 0) {
    stpart[threadIdx.x] = 0.f;
    stpart[256 + threadIdx.x] = 0.f;
  }
  const float* base = feat + (size_t)row * HW2;
  float s = 0.f;
  #pragma unroll
  for (int i = 0; i < 9; ++i) {
    float4 v = *(const float4*)(base + (size_t)(i * 256 + threadIdx.x) * 4);
    s += v.x + v.y + v.z + v.w;
  }
  #pragma unroll
  for (int off = 32; off > 0; off >>= 1) s += __shfl_down(s, off);
  __shared__ float ls[4];
  if ((threadIdx.x & 63) == 0) ls[threadIdx.x >> 6] = s;
  __syncthreads();
  if (threadIdx.x == 0) pooled[row] = ls[0] + ls[1] + ls[2] + ls[3];
}

// ---- kernel 2: SE mlp (recomputed per block) + conv_weight bf16 ------------
__global__ __launch_bounds__(256) void k_secw(
    const float* __restrict__ pooled, const float* __restrict__ w1,
    const float* __restrict__ b1, const float* __restrict__ w2,
    const float* __restrict__ b2, const float* __restrict__ w_red,
    unsigned short* __restrict__ cw) {
  const int b = blockIdx.x >> 8;           // 256 blocks per batch
  const int r = threadIdx.x & 63, q = threadIdx.x >> 6;
  __shared__ float part[4][64];
  __shared__ float hid[64];
  __shared__ float s4[4];
  {
    const float* pp = pooled + b * CIN + q * 256;
    const float* wrow = w1 + (size_t)r * CIN + q * 256;
    float acc = 0.f;
    for (int c = 0; c < 256; ++c) acc += pp[c] * wrow[c];
    part[q][r] = acc;
  }
  __syncthreads();
  if (q == 0) {
    float h = (part[0][r] + part[1][r] + part[2][r] + part[3][r]) *
                  (1.f / (float)HW2) + b1[r];
    hid[r] = h > 0.f ? h : 0.f;
  }
  __syncthreads();
  if (threadIdx.x < NSH) {
    float a = 0.f;
    for (int k = 0; k < RHID; ++k) a += hid[k] * w2[threadIdx.x * RHID + k];
    s4[threadIdx.x] = 1.f / (1.f + expf(-(a + b2[threadIdx.x])));
  }
  __syncthreads();
  int e4 = (blockIdx.x * 256 + threadIdx.x) * 4;   // < 8*256*1024
  int rem = e4 & 262143;
  int i = rem & 1023;
  float sv = s4[i >> 8];
  float4 v = *(const float4*)(w_red + rem);
  ushort4 o;
  o.x = f2bf(v.x * sv); o.y = f2bf(v.y * sv);
  o.z = f2bf(v.z * sv); o.w = f2bf(v.w * sv);
  *(ushort4*)(cw + e4) = o;
}

// ---- kernel 3: batched GEMM (R3 structure + A-swz + repacked C) ------------
// BM=256, BN=128, BK=32; 512 thr = 8 waves (4M x 2N), wave tile 64x64.
__device__ __forceinline__ void gl16(const void* g, void* l) {
  __builtin_amdgcn_global_load_lds(
      (const __attribute__((address_space(1))) unsigned int*)g,
      (__attribute__((address_space(3))) unsigned int*)l, 16, 0, 0);
}

__global__ __launch_bounds__(512, 4) void k_gemm(
    const float* __restrict__ feat, const unsigned short* __restrict__ cw,
    unsigned short* __restrict__ xb, float* __restrict__ stpart) {
  __shared__ unsigned char ldsb[69632];      // union: stage 40KB | X 68KB
  unsigned short* As  = (unsigned short*)ldsb;   // [256][32]
  unsigned short* BsT = As + 256 * 32;           // [128][32]
  const int nt = blockIdx.x, b = blockIdx.y;
  const int p0 = nt * 128;
  const int tid = threadIdx.x, lane = tid & 63, w = tid >> 6;
  const int wr = w >> 1, wc = w & 1;
  const unsigned short* cwb = cw + (size_t)b * COUT * CIN;
  const float* fbb = feat + (size_t)b * CIN * HW2;

  const int sn = tid & 127;
  const int skb = tid >> 7;
  const int sswz = (sn & 3) ^ ((sn >> 2) & 3);
  const float* bsrc0 = fbb + (size_t)(skb * 8) * HW2 + p0 + sn;

  // A source pre-swizzle (m173): LDS[row][c] = G[row][c ^ ((row>>1)&3)]
  int aoff[2];
  #pragma unroll
  for (int q = 0; q < 2; ++q) {
    int t = q * 512 + tid;
    int row = t >> 2;
    aoff[q] = row * CIN + ((t & 3) ^ ((row >> 1) & 3)) * 8;
  }

  f32x4 acc[4][4] = {};

  for (int k0 = 0; k0 < CIN; k0 += 32) {
    __syncthreads();
    #pragma unroll
    for (int q = 0; q < 2; ++q)
      gl16(cwb + aoff[q] + k0, &As[(q * 512 + w * 64) * 8]);
    {
      const float* src = bsrc0 + (size_t)k0 * HW2;
      float v[8];
      #pragma unroll
      for (int j = 0; j < 8; ++j) v[j] = src[(size_t)j * HW2];
      bf16x8 pk;
      #pragma unroll
      for (int j = 0; j < 8; ++j) pk[j] = (short)f2bf(v[j]);
      *(bf16x8*)&BsT[sn * 32 + ((skb ^ sswz) * 8)] = pk;
    }
    __syncthreads();

    bf16x8 af[4];
    #pragma unroll
    for (int mi = 0; mi < 4; ++mi) {
      int row = wr * 64 + mi * 16 + (lane & 15);
      af[mi] = *(const bf16x8*)&As[row * 32 +
                                   (((lane >> 4) ^ ((row >> 1) & 3)) * 8)];
    }
    bf16x8 bfv[4];
    #pragma unroll
    for (int ni = 0; ni < 4; ++ni) {
      int n = wc * 64 + ni * 16 + (lane & 15);
      int swz = (n & 3) ^ ((n >> 2) & 3);
      bfv[ni] = *(const bf16x8*)&BsT[n * 32 + (((lane >> 4) ^ swz) * 8)];
    }
    #pragma unroll
    for (int mi = 0; mi < 4; ++mi)
      #pragma unroll
      for (int ni = 0; ni < 4; ++ni)
        acc[mi][ni] = __builtin_amdgcn_mfma_f32_16x16x32_bf16(
            af[mi], bfv[ni], acc[mi][ni], 0, 0, 0);
  }

  // ---- fused GN partial stats (register-only): g = 8wr+2mi+(lane>=32) ----
  #pragma unroll
  for (int mi = 0; mi < 4; ++mi) {
    float s1 = 0.f, s2 = 0.f;
    #pragma unroll
    for (int ni = 0; ni < 4; ++ni)
      #pragma unroll
      for (int j = 0; j < 4; ++j) {
        float v = acc[mi][ni][j];
        s1 += v; s2 += v * v;
      }
    #pragma unroll
    for (int off = 1; off <= 16; off <<= 1) {
      s1 += __shfl_xor(s1, off);
      s2 += __shfl_xor(s2, off);
    }
    if ((lane & 31) == 0) {
      int g = 8 * wr + 2 * mi + (lane >> 5);
      atomicAdd(&stpart[(b * 32 + g) * 2], s1);
      atomicAdd(&stpart[(b * 32 + g) * 2 + 1], s2);
    }
  }

  // ---- epilogue: repack acc -> LDS X[256][136], then 128-B-run stores ----
  __syncthreads();                         // all stage-LDS readers done
  unsigned short* X = (unsigned short*)ldsb;
  #pragma unroll
  for (int mi = 0; mi < 4; ++mi) {
    int r0 = wr * 64 + mi * 16 + ((lane >> 4) << 2);
    #pragma unroll
    for (int ni = 0; ni < 4; ++ni) {
      int c = wc * 64 + ni * 16 + (lane & 15);
      #pragma unroll
      for (int j = 0; j < 4; ++j)
        X[(r0 + j) * 136 + c] = f2bf(acc[mi][ni][j]);
    }
  }
  __syncthreads();
  unsigned short* ob = xb + (size_t)b * COUT * HW2 + p0;
  #pragma unroll
  for (int i = 0; i < 8; ++i) {
    int v = i * 512 + tid;       // 4096 chunks of 8 bf16
    int row = v >> 4, c = v & 15;
    bf16x8 val = *(const bf16x8*)&X[row * 136 + c * 8];
    *(bf16x8*)&ob[(size_t)row * HW2 + c * 8] = val;
  }
}

// ---- kernel 4: GN finalize (inline) + apply + ReLU -------------------------
__global__ __launch_bounds__(256) void k_apply(
    const unsigned short* __restrict__ xb, float* __restrict__ out,
    const float* __restrict__ stpart, const float* __restrict__ gamma,
    const float* __restrict__ beta) {
  const float inv = 1.f / (float)GRPSZ;
  #pragma unroll
  for (int i = 0; i < 4; ++i) {
    unsigned e = ((unsigned)blockIdx.x * 1024 + i * 256 + threadIdx.x) * 4;
    unsigned row = (e >> 10) / 9;   // e / 9216
    int o = row & 255;
    int bg = row >> 3;              // b*32 + o/8
    float mu = stpart[bg * 2] * inv;
    float rs = rsqrtf(stpart[bg * 2 + 1] * inv - mu * mu + EPSV);
    float g = gamma[o] * rs;
    float bb = beta[o] - mu * g;
    ushort4 v = *(const ushort4*)(xb + e);
    float4 r;
    r.x = fmaxf(bf2f(v.x) * g + bb, 0.f);
    r.y = fmaxf(bf2f(v.y) * g + bb, 0.f);
    r.z = fmaxf(bf2f(v.z) * g + bb, 0.f);
    r.w = fmaxf(bf2f(v.w) * g + bb, 0.f);
    *(float4*)(out + e) = r;
  }
}

extern "C" void kernel_launch(void* const* d_in, const int* in_sizes, int n_in,
                              void* d_out, int out_size, void* d_ws, size_t ws_size,
                              hipStream_t stream) {
  const float* feat  = (const float*)d_in[0];
  const float* w1    = (const float*)d_in[1];
  const float* b1    = (const float*)d_in[2];
  const float* w2    = (const float*)d_in[3];
  const float* b2    = (const float*)d_in[4];
  const float* w_red = (const float*)d_in[5];
  const float* gamma = (const float*)d_in[6];
  const float* beta  = (const float*)d_in[7];
  float* out = (float*)d_out;

  char* ws = (char*)d_ws;
  unsigned short* cw = (unsigned short*)ws;            //  4,194,304 B
  unsigned short* xb = (unsigned short*)(ws + 4194304);//  37,748,736 B
  float* pooled = (float*)(ws + 41943040);             //     32,768 B
  float* stpart = (float*)(ws + 41975808);             //      2,048 B
  // total ws need: ~42 MB

  k_pool<<<8192, 256, 0, stream>>>(feat, pooled, stpart);
  k_secw<<<2048, 256, 0, stream>>>(pooled, w1, b1, w2, b2, w_red, cw);
  k_gemm<<<dim3(72, 8), 512, 0, stream>>>(feat, cw, xb, stpart);
  k_apply<<<4608, 256, 0, stream>>>(xb, out, stpart, gamma, beta);
}